// Round 1
// baseline (1191.440 us; speedup 1.0000x reference)
//
#include <hip/hip_runtime.h>

// Problem constants (from reference)
#define B_TRAJ 16384
#define T_STEPS 60
#define D_IN 36
#define L_DIM 10
#define C_NUM 20
#define S_STAT 9
#define OUT_DIM 8

__device__ __forceinline__ float rcp_fast(float x) { return __builtin_amdgcn_rcpf(x); }

__device__ __forceinline__ float sigm_fast(float x) {
    // 1/(1+exp(-x)); __expf -> v_exp_f32 based, plenty accurate for 0.088 absmax threshold
    return rcp_fast(1.0f + __expf(-x));
}

__device__ __forceinline__ float tanh_fast(float x) {
    // clamp to avoid inf/inf; tanh saturates anyway
    x = fminf(fmaxf(x, -10.0f), 10.0f);
    float e = __expf(2.0f * x);
    return (e - 1.0f) * rcp_fast(e + 1.0f);
}

__global__ __launch_bounds__(64, 1) void dgm2_fused_scan(
    const float* __restrict__ data,        // [B, T, D]
    const float* __restrict__ time_steps,  // [T]
    const float* __restrict__ static_data, // [B, S]
    const float* __restrict__ W_update,    // [L+D, L]
    const float* __restrict__ b_update,    // [L]
    const float* __restrict__ W_reset,     // [L+D, L]
    const float* __restrict__ b_reset,     // [L]
    const float* __restrict__ W_new,       // [L+D, L]
    const float* __restrict__ b_new,       // [L]
    const float* __restrict__ W_emit,      // [C+L, C]
    const float* __restrict__ b_emit,      // [C]
    const float* __restrict__ W_ode,       // [L, L]
    const float* __restrict__ b_ode,       // [L]
    const float* __restrict__ W_mlp,       // [T*L+S, OUT]
    const float* __restrict__ b_mlp,       // [OUT]
    float* __restrict__ out)               // [B, OUT]
{
    const int b = blockIdx.x * blockDim.x + threadIdx.x;
    if (b >= B_TRAJ) return;

    float y[L_DIM];        // y_state (carry)
    float p[C_NUM];        // y_prob  (carry)
    float o8[OUT_DIM];     // fused MLP-head accumulator

#pragma unroll
    for (int i = 0; i < L_DIM; ++i) y[i] = 0.0f;
#pragma unroll
    for (int i = 0; i < C_NUM; ++i) p[i] = 0.0f;
#pragma unroll
    for (int i = 0; i < OUT_DIM; ++i) o8[i] = 0.0f;

    const float* xbase = data + (size_t)b * (T_STEPS * D_IN);

    float xc[D_IN];  // current x_t
    float xn[D_IN];  // prefetched x_{t+1}

    // prefetch t = 0 (16B-aligned: b*2160*4 and t*144 are both 16B multiples)
#pragma unroll
    for (int q = 0; q < D_IN / 4; ++q) {
        float4 v = reinterpret_cast<const float4*>(xbase)[q];
        xc[4 * q + 0] = v.x; xc[4 * q + 1] = v.y;
        xc[4 * q + 2] = v.z; xc[4 * q + 3] = v.w;
    }

    for (int t = 0; t < T_STEPS; ++t) {
        // prefetch next step's observation while computing this one
        if (t + 1 < T_STEPS) {
#pragma unroll
            for (int q = 0; q < D_IN / 4; ++q) {
                float4 v = reinterpret_cast<const float4*>(xbase + (t + 1) * D_IN)[q];
                xn[4 * q + 0] = v.x; xn[4 * q + 1] = v.y;
                xn[4 * q + 2] = v.z; xn[4 * q + 3] = v.w;
            }
        }

        // dt: first step uses synthetic 0.01, then consecutive diffs (scalar loads)
        float dt = (t == 0) ? 0.01f : (time_steps[t] - time_steps[t - 1]);

        // ---- Euler ODE step: yi = y + tanh(y @ W_ode + b_ode) * dt ----
        float g[L_DIM];
#pragma unroll
        for (int j = 0; j < L_DIM; ++j) g[j] = b_ode[j];
#pragma unroll
        for (int k = 0; k < L_DIM; ++k) {
            float yk = y[k];
#pragma unroll
            for (int j = 0; j < L_DIM; ++j) g[j] += yk * W_ode[k * L_DIM + j];
        }
        float yi[L_DIM];
#pragma unroll
        for (int j = 0; j < L_DIM; ++j) yi[j] = y[j] + tanh_fast(g[j]) * dt;

        // ---- GRU gates: u = sig(yc@Wu+bu), r = sig(yc@Wr+br), yc=[yi, x] ----
        float u[L_DIM], r[L_DIM];
#pragma unroll
        for (int j = 0; j < L_DIM; ++j) { u[j] = b_update[j]; r[j] = b_reset[j]; }
#pragma unroll
        for (int k = 0; k < L_DIM; ++k) {
            float yk = yi[k];
#pragma unroll
            for (int j = 0; j < L_DIM; ++j) {
                u[j] += yk * W_update[k * L_DIM + j];
                r[j] += yk * W_reset[k * L_DIM + j];
            }
        }
#pragma unroll
        for (int k = 0; k < D_IN; ++k) {
            float xk = xc[k];
#pragma unroll
            for (int j = 0; j < L_DIM; ++j) {
                u[j] += xk * W_update[(L_DIM + k) * L_DIM + j];
                r[j] += xk * W_reset[(L_DIM + k) * L_DIM + j];
            }
        }
#pragma unroll
        for (int j = 0; j < L_DIM; ++j) { u[j] = sigm_fast(u[j]); r[j] = sigm_fast(r[j]); }

        // ---- candidate: new = cc @ W_new + b_new, cc = [yi*r, x] ----
        float nw[L_DIM];
#pragma unroll
        for (int j = 0; j < L_DIM; ++j) nw[j] = b_new[j];
#pragma unroll
        for (int k = 0; k < L_DIM; ++k) {
            float cr = yi[k] * r[k];
#pragma unroll
            for (int j = 0; j < L_DIM; ++j) nw[j] += cr * W_new[k * L_DIM + j];
        }
#pragma unroll
        for (int k = 0; k < D_IN; ++k) {
            float xk = xc[k];
#pragma unroll
            for (int j = 0; j < L_DIM; ++j) nw[j] += xk * W_new[(L_DIM + k) * L_DIM + j];
        }
        // y_new = (1-u)*new + u*yi  ==  new + u*(yi-new)
#pragma unroll
        for (int j = 0; j < L_DIM; ++j) y[j] = nw[j] + u[j] * (yi[j] - nw[j]);

        // ---- emitter: p = softmax([p, y_new] @ W_emit + b_emit) ----
        float e[C_NUM];
#pragma unroll
        for (int j = 0; j < C_NUM; ++j) e[j] = b_emit[j];
#pragma unroll
        for (int k = 0; k < C_NUM; ++k) {
            float pk = p[k];
#pragma unroll
            for (int j = 0; j < C_NUM; ++j) e[j] += pk * W_emit[k * C_NUM + j];
        }
#pragma unroll
        for (int k = 0; k < L_DIM; ++k) {
            float yk = y[k];
#pragma unroll
            for (int j = 0; j < C_NUM; ++j) e[j] += yk * W_emit[(C_NUM + k) * C_NUM + j];
        }
        float m = e[0];
#pragma unroll
        for (int j = 1; j < C_NUM; ++j) m = fmaxf(m, e[j]);
        float s = 0.0f;
#pragma unroll
        for (int j = 0; j < C_NUM; ++j) { p[j] = __expf(e[j] - m); s += p[j]; }
        float inv = rcp_fast(s);
#pragma unroll
        for (int j = 0; j < C_NUM; ++j) p[j] *= inv;

        // ---- fused MLP head: o8 += y_new . W_mlp[t*L + l, :] ----
        const float* wm = W_mlp + (size_t)t * L_DIM * OUT_DIM;
#pragma unroll
        for (int l = 0; l < L_DIM; ++l) {
            float yl = y[l];
#pragma unroll
            for (int o = 0; o < OUT_DIM; ++o) o8[o] += yl * wm[l * OUT_DIM + o];
        }

        // rotate prefetch buffer
#pragma unroll
        for (int i = 0; i < D_IN; ++i) xc[i] = xn[i];
    }

    // ---- static tail + bias ----
    const float* st = static_data + (size_t)b * S_STAT;
    const float* wms = W_mlp + (size_t)(T_STEPS * L_DIM) * OUT_DIM;
#pragma unroll
    for (int s2 = 0; s2 < S_STAT; ++s2) {
        float sv = st[s2];
#pragma unroll
        for (int o = 0; o < OUT_DIM; ++o) o8[o] += sv * wms[s2 * OUT_DIM + o];
    }
#pragma unroll
    for (int o = 0; o < OUT_DIM; ++o) out[(size_t)b * OUT_DIM + o] = o8[o] + b_mlp[o];
}

extern "C" void kernel_launch(void* const* d_in, const int* in_sizes, int n_in,
                              void* d_out, int out_size, void* d_ws, size_t ws_size,
                              hipStream_t stream) {
    const float* data        = (const float*)d_in[0];
    const float* time_steps  = (const float*)d_in[1];
    const float* static_data = (const float*)d_in[2];
    const float* W_update    = (const float*)d_in[3];
    const float* b_update    = (const float*)d_in[4];
    const float* W_reset     = (const float*)d_in[5];
    const float* b_reset     = (const float*)d_in[6];
    const float* W_new       = (const float*)d_in[7];
    const float* b_new       = (const float*)d_in[8];
    const float* W_emit      = (const float*)d_in[9];
    const float* b_emit      = (const float*)d_in[10];
    const float* W_ode       = (const float*)d_in[11];
    const float* b_ode       = (const float*)d_in[12];
    const float* W_mlp       = (const float*)d_in[13];
    const float* b_mlp       = (const float*)d_in[14];
    float* out = (float*)d_out;

    // 64-thread blocks -> 256 workgroups -> one per CU (16384 trajectories total)
    dim3 grid(B_TRAJ / 64), block(64);
    hipLaunchKernelGGL(dgm2_fused_scan, grid, block, 0, stream,
                       data, time_steps, static_data,
                       W_update, b_update, W_reset, b_reset, W_new, b_new,
                       W_emit, b_emit, W_ode, b_ode, W_mlp, b_mlp, out);
}

// Round 2
// 653.164 us; speedup vs baseline: 1.8241x; 1.8241x over previous
//
#include <hip/hip_runtime.h>

// Problem constants (from reference)
#define B_TRAJ 16384
#define T_STEPS 60
#define D_IN 36
#define L_DIM 10
#define C_NUM 20
#define S_STAT 9
#define OUT_DIM 8

__device__ __forceinline__ float rcp_fast(float x) { return __builtin_amdgcn_rcpf(x); }
__device__ __forceinline__ float sigm_fast(float x) { return rcp_fast(1.0f + __expf(-x)); }
__device__ __forceinline__ float tanh_fast(float x) {
    x = fminf(fmaxf(x, -10.0f), 10.0f);
    float e = __expf(2.0f * x);
    return (e - 1.0f) * rcp_fast(e + 1.0f);
}

// Lane layout: 64 lanes = 4 trajectories x 16 column-slots.
//  slot < 10 : owns column `slot` of W_update/W_reset/W_new/W_ode (GRU owner)
//  slot 0-15 : owns column `slot` of W_emit (e1)
//  slot 10-13: ALSO owns column 16+(slot-10) of W_emit (e2) — weights aliased
//              into the (otherwise unused) wu[] array of those lanes.
//  slot < 8  : owns output column `slot` of W_mlp head.
// State y is replicated per-lane; yi-delta / r / y_new / p are broadcast
// through tiny LDS buffers (1-wave blocks -> __syncthreads is ~free).
__global__ __launch_bounds__(64, 2) void dgm2_jsplit(
    const float* __restrict__ data,        // [B, T, D]
    const float* __restrict__ time_steps,  // [T]
    const float* __restrict__ static_data, // [B, S]
    const float* __restrict__ W_update,    // [46, 10]
    const float* __restrict__ b_update,
    const float* __restrict__ W_reset,     // [46, 10]
    const float* __restrict__ b_reset,
    const float* __restrict__ W_new,       // [46, 10]
    const float* __restrict__ b_new,
    const float* __restrict__ W_emit,      // [30, 20]
    const float* __restrict__ b_emit,
    const float* __restrict__ W_ode,       // [10, 10]
    const float* __restrict__ b_ode,
    const float* __restrict__ W_mlp,       // [609, 8]
    const float* __restrict__ b_mlp,
    float* __restrict__ out)               // [B, 8]
{
    __shared__ float xs[2][4][36];         // double-buffered x_t per traj
    __shared__ float bcA[4][12];           // ODE delta broadcast
    __shared__ float bcB[4][12];           // r broadcast
    __shared__ float bcC[4][12];           // y_new broadcast
    __shared__ float bcP[4][20];           // p (softmax output) broadcast

    const int lane = threadIdx.x;
    const int slot = lane & 15;
    const int tl   = lane >> 4;            // trajectory-local 0..3
    const int traj0 = blockIdx.x * 4;
    const bool gru = (slot < L_DIM);
    const bool e2o = (slot >= 10 && slot < 14);   // owns e-col 16..19
    const bool oo  = (slot < OUT_DIM);

    // x-staging role (lane-invariant over t)
    const int st_t = lane / 9;             // traj-local for staging
    const int st_c = lane % 9;             // float4 chunk index
    const bool stager = (lane < 36);

    // ---- one-time: load register-resident weight columns ----
    float wu[46], wr[46], wn[46];
#pragma unroll
    for (int k = 0; k < 46; ++k) {
        float wuv = 0.0f;
        if (gru) wuv = W_update[k * L_DIM + slot];
        else if (e2o && k < 30) wuv = W_emit[k * C_NUM + (slot + 6)]; // e2 col = 16+(slot-10)
        wu[k] = wuv;
        wr[k] = gru ? W_reset[k * L_DIM + slot] : 0.0f;
        wn[k] = gru ? W_new[k * L_DIM + slot]   : 0.0f;
    }
    float wode[L_DIM];
#pragma unroll
    for (int k = 0; k < L_DIM; ++k) wode[k] = gru ? W_ode[k * L_DIM + slot] : 0.0f;
    float we1[30];
#pragma unroll
    for (int k = 0; k < 30; ++k) we1[k] = W_emit[k * C_NUM + slot];  // slot always <16<20

    const float b0  = gru ? b_ode[slot]    : 0.0f;
    const float bu  = gru ? b_update[slot] : 0.0f;
    const float brr = gru ? b_reset[slot]  : 0.0f;
    const float bnn = gru ? b_new[slot]    : 0.0f;
    const float be1 = b_emit[slot];
    const float be2 = e2o ? b_emit[slot + 6] : 0.0f;

    // ---- stage x_0; zero p; preload W_mlp col for t=0 ----
    if (stager) {
        const float4 v = *reinterpret_cast<const float4*>(
            data + ((size_t)(traj0 + st_t) * T_STEPS + 0) * D_IN + st_c * 4);
        *reinterpret_cast<float4*>(&xs[0][st_t][st_c * 4]) = v;
    }
    bcP[tl][slot] = 0.0f;
    if (e2o) bcP[tl][slot + 6] = 0.0f;

    float wm[L_DIM];
#pragma unroll
    for (int l = 0; l < L_DIM; ++l)
        wm[l] = oo ? W_mlp[(0 * L_DIM + l) * OUT_DIM + slot] : 0.0f;

    float y[L_DIM];
#pragma unroll
    for (int k = 0; k < L_DIM; ++k) y[k] = 0.0f;
    float o8 = 0.0f;

    __syncthreads();

    for (int t = 0; t < T_STEPS; ++t) {
        const int cur = t & 1, nxt = cur ^ 1;
        const float dt = (t == 0) ? 0.01f : (time_steps[t] - time_steps[t - 1]);

        // ---- ODE: g_j = b0 + sum_k y[k] * Wode[k][j]; delta_j = tanh(g)*dt ----
        float g = b0;
#pragma unroll
        for (int k = 0; k < L_DIM; ++k) g += y[k] * wode[k];
        const float d_j = tanh_fast(g) * dt;
        if (gru) bcA[tl][slot] = d_j;
        __syncthreads();                                   // S1

        // prefetch next x into registers (drained at S2; gates give slack)
        float4 xr = make_float4(0.f, 0.f, 0.f, 0.f);
        if (stager && (t + 1 < T_STEPS)) {
            xr = *reinterpret_cast<const float4*>(
                data + ((size_t)(traj0 + st_t) * T_STEPS + (t + 1)) * D_IN + st_c * 4);
        }

        // replicate yi; capture own element
        float yiv[L_DIM];
        float yij = 0.0f;
#pragma unroll
        for (int k = 0; k < L_DIM; ++k) {
            yiv[k] = y[k] + bcA[tl][k];
            if (slot == k) yij = yiv[k];
        }

        // ---- gates u, r over [yi, x] ----
        float u = bu, r = brr;
#pragma unroll
        for (int k = 0; k < L_DIM; ++k) { u += yiv[k] * wu[k]; r += yiv[k] * wr[k]; }
#pragma unroll
        for (int c = 0; c < 9; ++c) {
            const float4 x4 = *reinterpret_cast<const float4*>(&xs[cur][tl][c * 4]);
            const int kk = L_DIM + c * 4;
            u += x4.x * wu[kk] + x4.y * wu[kk + 1] + x4.z * wu[kk + 2] + x4.w * wu[kk + 3];
            r += x4.x * wr[kk] + x4.y * wr[kk + 1] + x4.z * wr[kk + 2] + x4.w * wr[kk + 3];
        }
        u = sigm_fast(u);
        r = sigm_fast(r);
        if (gru) bcB[tl][slot] = r;
        __syncthreads();                                   // S2

        // ---- candidate: nw_j over [yi*r, x] ----
        float rv[L_DIM];
#pragma unroll
        for (int k = 0; k < L_DIM; ++k) rv[k] = bcB[tl][k];
        float nw = bnn;
#pragma unroll
        for (int k = 0; k < L_DIM; ++k) nw += (yiv[k] * rv[k]) * wn[k];
#pragma unroll
        for (int c = 0; c < 9; ++c) {
            const float4 x4 = *reinterpret_cast<const float4*>(&xs[cur][tl][c * 4]);
            const int kk = L_DIM + c * 4;
            nw += x4.x * wn[kk] + x4.y * wn[kk + 1] + x4.z * wn[kk + 2] + x4.w * wn[kk + 3];
        }
        const float ynj = nw + u * (yij - nw);
        if (gru) bcC[tl][slot] = ynj;
        __syncthreads();                                   // S3

        // replicate y_new into y
#pragma unroll
        for (int k = 0; k < L_DIM; ++k) y[k] = bcC[tl][k];

        // ---- emitter: e = [p, y_new] @ W_emit + b ----
        float e1 = be1, e2 = be2;
#pragma unroll
        for (int q = 0; q < 5; ++q) {
            const float4 p4 = *reinterpret_cast<const float4*>(&bcP[tl][q * 4]);
            const int kk = q * 4;
            e1 += p4.x * we1[kk] + p4.y * we1[kk + 1] + p4.z * we1[kk + 2] + p4.w * we1[kk + 3];
            e2 += p4.x * wu[kk]  + p4.y * wu[kk + 1]  + p4.z * wu[kk + 2]  + p4.w * wu[kk + 3];
        }
#pragma unroll
        for (int k = 0; k < L_DIM; ++k) {
            e1 += y[k] * we1[20 + k];
            e2 += y[k] * wu[20 + k];
        }

        // ---- distributed softmax over the 16-lane group (20 logits) ----
        float mx = e2o ? fmaxf(e1, e2) : e1;
#pragma unroll
        for (int m = 1; m < 16; m <<= 1) mx = fmaxf(mx, __shfl_xor(mx, m, 16));
        const float z1 = __expf(e1 - mx);
        const float z2 = e2o ? __expf(e2 - mx) : 0.0f;
        float sm = z1 + z2;
#pragma unroll
        for (int m = 1; m < 16; m <<= 1) sm += __shfl_xor(sm, m, 16);
        const float inv = rcp_fast(sm);
        bcP[tl][slot] = z1 * inv;                 // cols 0..15
        if (e2o) bcP[tl][slot + 6] = z2 * inv;    // cols 16..19

        // ---- fused MLP head ----
#pragma unroll
        for (int l = 0; l < L_DIM; ++l) o8 += y[l] * wm[l];
        if (t + 1 < T_STEPS) {
#pragma unroll
            for (int l = 0; l < L_DIM; ++l)
                wm[l] = oo ? W_mlp[((size_t)(t + 1) * L_DIM + l) * OUT_DIM + slot] : 0.0f;
        }

        // ---- commit staged x_{t+1} ----
        if (stager && (t + 1 < T_STEPS))
            *reinterpret_cast<float4*>(&xs[nxt][st_t][st_c * 4]) = xr;
        __syncthreads();                                   // S4
    }

    // ---- static tail + bias + store ----
    if (oo) {
        const int traj = traj0 + tl;
        const float* st = static_data + (size_t)traj * S_STAT;
        const float* wms = W_mlp + (size_t)(T_STEPS * L_DIM) * OUT_DIM;
#pragma unroll
        for (int s = 0; s < S_STAT; ++s) o8 += st[s] * wms[s * OUT_DIM + slot];
        out[(size_t)traj * OUT_DIM + slot] = o8 + b_mlp[slot];
    }
}

extern "C" void kernel_launch(void* const* d_in, const int* in_sizes, int n_in,
                              void* d_out, int out_size, void* d_ws, size_t ws_size,
                              hipStream_t stream) {
    const float* data        = (const float*)d_in[0];
    const float* time_steps  = (const float*)d_in[1];
    const float* static_data = (const float*)d_in[2];
    const float* W_update    = (const float*)d_in[3];
    const float* b_update    = (const float*)d_in[4];
    const float* W_reset     = (const float*)d_in[5];
    const float* b_reset     = (const float*)d_in[6];
    const float* W_new       = (const float*)d_in[7];
    const float* b_new       = (const float*)d_in[8];
    const float* W_emit      = (const float*)d_in[9];
    const float* b_emit      = (const float*)d_in[10];
    const float* W_ode       = (const float*)d_in[11];
    const float* b_ode       = (const float*)d_in[12];
    const float* W_mlp       = (const float*)d_in[13];
    const float* b_mlp       = (const float*)d_in[14];
    float* out = (float*)d_out;

    // 4 trajectories per 64-thread block -> 4096 blocks = 4096 waves (16x round 1)
    dim3 grid(B_TRAJ / 4), block(64);
    hipLaunchKernelGGL(dgm2_jsplit, grid, block, 0, stream,
                       data, time_steps, static_data,
                       W_update, b_update, W_reset, b_reset, W_new, b_new,
                       W_emit, b_emit, W_ode, b_ode, W_mlp, b_mlp, out);
}

// Round 3
// 470.328 us; speedup vs baseline: 2.5332x; 1.3887x over previous
//
#include <hip/hip_runtime.h>
#include <math.h>

// Problem constants (from reference)
#define B_TRAJ 16384
#define T_STEPS 60
#define D_IN 36
#define L_DIM 10
#define C_NUM 20
#define S_STAT 9
#define OUT_DIM 8

__device__ __forceinline__ float rcp_fast(float x) { return __builtin_amdgcn_rcpf(x); }
__device__ __forceinline__ float sigm_fast(float x) { return rcp_fast(1.0f + __expf(-x)); }
__device__ __forceinline__ float tanh_fast(float x) {
    x = fminf(fmaxf(x, -10.0f), 10.0f);
    float e = __expf(2.0f * x);
    return (e - 1.0f) * rcp_fast(e + 1.0f);
}
#define WFENCE() __builtin_amdgcn_wave_barrier()

// 32 lanes per trajectory, 2 trajectories per wave, 4 waves per block.
// Slot roles (s = lane & 31):
//   s 0-9  : u-column s   ; wx[0..9] = W_ode col s ; (s<8: wx[10..19] = streamed W_mlp col s)
//   s 10-19: r-column s-10; wx[0..29] = W_emit col s-10
//   s 20-29: n-column s-20; wx[0..29] = W_emit col s-10 (cols 10..19)
//   s 30,31: inert (zero weights)
// All cross-lane traffic is intra-wave (LDS in-order per wave + wave_barrier) — no __syncthreads.
__global__ __launch_bounds__(256, 4) void dgm2_32lane(
    const float* __restrict__ data,        // [B, T, D]
    const float* __restrict__ time_steps,  // [T]
    const float* __restrict__ static_data, // [B, S]
    const float* __restrict__ W_update,    // [46, 10]
    const float* __restrict__ b_update,
    const float* __restrict__ W_reset,     // [46, 10]
    const float* __restrict__ b_reset,
    const float* __restrict__ W_new,       // [46, 10]
    const float* __restrict__ b_new,
    const float* __restrict__ W_emit,      // [30, 20]
    const float* __restrict__ b_emit,
    const float* __restrict__ W_ode,       // [10, 10]
    const float* __restrict__ b_ode,
    const float* __restrict__ W_mlp,       // [609, 8]
    const float* __restrict__ b_mlp,
    float* __restrict__ out)               // [B, 8]
{
    __shared__ float xs[4][2][2][40];   // [wave][buf][half][36 padded] x_t staging
    __shared__ float bcD[4][2][12];     // ODE delta
    __shared__ float bcR[4][2][12];     // r gate
    __shared__ float bcN[4][2][12];     // raw candidate n
    __shared__ float bcY[4][2][12];     // y_new
    __shared__ float bcP[4][2][20];     // softmax p

    const int tid  = threadIdx.x;
    const int w    = tid >> 6;          // wave in block
    const int lane = tid & 63;
    const int s    = lane & 31;         // slot within trajectory group
    const int half = lane >> 5;         // trajectory within wave
    const int traj = blockIdx.x * 8 + w * 2 + half;

    const bool uo = (s < 10);
    const bool ro = (s >= 10 && s < 20);
    const bool no = (s >= 20 && s < 30);
    const bool eo = (s >= 10 && s < 30);   // emit col s-10
    const bool oo = (s < OUT_DIM);         // head col s
    const int  gcol = uo ? s : (ro ? (s - 10) : (no ? (s - 20) : 0));
    const int  ecol = s - 10;

    // x stagers: lanes 0..17 of each wave (2 halves x 9 float4 chunks)
    const bool stager = (lane < 18);
    const int  st_h = lane / 9, st_c = lane % 9;
    const int  st_traj = blockIdx.x * 8 + w * 2 + st_h;

    // ---- one-time weight loads (<=86 regs) ----
    const float* Wg = uo ? W_update : (ro ? W_reset : W_new);
    float wg[46];
#pragma unroll
    for (int k = 0; k < 46; ++k) wg[k] = (s < 30) ? Wg[k * L_DIM + gcol] : 0.0f;

    float wx[30];
#pragma unroll
    for (int k = 0; k < 30; ++k) {
        float v = 0.0f;
        if (eo) v = W_emit[k * C_NUM + ecol];
        else if (uo && k < 10) v = W_ode[k * L_DIM + s];
        wx[k] = v;
    }
    if (oo) {   // stream W_mlp col for t=0 into wx[10..19] (unused slots on u-lanes)
#pragma unroll
        for (int l = 0; l < L_DIM; ++l) wx[10 + l] = W_mlp[l * OUT_DIM + s];
    }

    const float bg = uo ? b_update[s] : (ro ? b_reset[ecol] : (no ? b_new[ecol] : 0.0f));
    const float bx = uo ? b_ode[s] : (eo ? b_emit[ecol] : 0.0f);

    // ---- init state ----
    float y[L_DIM];
#pragma unroll
    for (int k = 0; k < L_DIM; ++k) y[k] = 0.0f;
    float yown = 0.0f;     // this uo-lane's own y element (tracked, avoids dynamic index)
    float o8 = 0.0f;

    if (stager) {
        const float4 v = *reinterpret_cast<const float4*>(
            data + (size_t)st_traj * (T_STEPS * D_IN) + st_c * 4);
        *reinterpret_cast<float4*>(&xs[w][0][st_h][st_c * 4]) = v;
    }
    if (eo) bcP[w][half][ecol] = 0.0f;
    WFENCE();

    for (int t = 0; t < T_STEPS; ++t) {
        const int cur = t & 1, nxt = cur ^ 1;
        const float dt = (t == 0) ? 0.01f : (time_steps[t] - time_steps[t - 1]);

        // ---- ODE: delta_s = tanh(b_ode + y.Wode_col_s) * dt (uo lanes) ----
        float g = bx;
#pragma unroll
        for (int k = 0; k < L_DIM; ++k) g += y[k] * wx[k];
        const float dv = tanh_fast(g) * dt;
        if (uo) bcD[w][half][s] = dv;
        WFENCE();

        // prefetch next x while LDS settles
        float4 xr = make_float4(0.f, 0.f, 0.f, 0.f);
        if (stager && (t + 1 < T_STEPS)) {
            xr = *reinterpret_cast<const float4*>(
                data + ((size_t)st_traj * T_STEPS + (t + 1)) * D_IN + st_c * 4);
        }

        // ---- y <- yi (replicate delta); own element via local dv ----
#pragma unroll
        for (int k = 0; k < L_DIM; ++k) y[k] += bcD[w][half][k];
        const float yij = yown + dv;   // valid on uo lanes

        // ---- gate dot products: accY over yi (u/r only), accX over x (all) ----
        float accY = 0.0f;
#pragma unroll
        for (int k = 0; k < L_DIM; ++k) accY += y[k] * wg[k];
        float accX = 0.0f, accX2 = 0.0f;
#pragma unroll
        for (int c = 0; c < 9; ++c) {
            const float4 x4 = *reinterpret_cast<const float4*>(&xs[w][cur][half][c * 4]);
            const int kk = L_DIM + c * 4;
            accX  += x4.x * wg[kk]     + x4.y * wg[kk + 1];
            accX2 += x4.z * wg[kk + 2] + x4.w * wg[kk + 3];
        }
        accX += accX2;

        float uval = 0.0f;
        if (uo) uval = sigm_fast(bg + accY + accX);
        if (ro) bcR[w][half][ecol] = sigm_fast(bg + accY + accX);
        WFENCE();

        // ---- candidate on n-lanes: n = b + sum (yi_k r_k) wn_k + x-part ----
        if (no) {
            float rv[L_DIM];
#pragma unroll
            for (int k = 0; k < L_DIM; ++k) rv[k] = bcR[w][half][k];
            float a = bg + accX;
#pragma unroll
            for (int k = 0; k < L_DIM; ++k) a += (y[k] * rv[k]) * wg[k];
            bcN[w][half][s - 20] = a;
        }
        WFENCE();

        // ---- blend on u-lanes: yn = n + u*(yi - n) ----
        if (uo) {
            const float nj = bcN[w][half][s];
            const float yn = nj + uval * (yij - nj);
            yown = yn;
            bcY[w][half][s] = yn;
        }
        WFENCE();
#pragma unroll
        for (int k = 0; k < L_DIM; ++k) y[k] = bcY[w][half][k];

        // ---- emitter (eo lanes own one of 20 logits) ----
        float ev = bx;
#pragma unroll
        for (int q = 0; q < 5; ++q) {
            const float4 p4 = *reinterpret_cast<const float4*>(&bcP[w][half][q * 4]);
            const int kk = q * 4;
            ev += p4.x * wx[kk] + p4.y * wx[kk + 1] + p4.z * wx[kk + 2] + p4.w * wx[kk + 3];
        }
#pragma unroll
        for (int k = 0; k < L_DIM; ++k) ev += y[k] * wx[20 + k];

        // softmax across the 32-lane group (20 live logits)
        float mx = eo ? ev : -INFINITY;
#pragma unroll
        for (int m = 1; m < 32; m <<= 1) mx = fmaxf(mx, __shfl_xor(mx, m, 32));
        const float z = eo ? __expf(ev - mx) : 0.0f;
        float sm = z;
#pragma unroll
        for (int m = 1; m < 32; m <<= 1) sm += __shfl_xor(sm, m, 32);
        if (eo) bcP[w][half][ecol] = z * rcp_fast(sm);

        // ---- fused head on oo lanes; stream next W_mlp column ----
        if (oo) {
#pragma unroll
            for (int l = 0; l < L_DIM; ++l) o8 += y[l] * wx[10 + l];
            if (t + 1 < T_STEPS) {
#pragma unroll
                for (int l = 0; l < L_DIM; ++l)
                    wx[10 + l] = W_mlp[((size_t)(t + 1) * L_DIM + l) * OUT_DIM + s];
            }
        }

        // ---- commit prefetched x_{t+1} ----
        if (stager && (t + 1 < T_STEPS))
            *reinterpret_cast<float4*>(&xs[w][nxt][st_h][st_c * 4]) = xr;
        WFENCE();
    }

    // ---- static tail + bias + store ----
    if (oo) {
        const float* st  = static_data + (size_t)traj * S_STAT;
        const float* wms = W_mlp + (size_t)(T_STEPS * L_DIM) * OUT_DIM;
#pragma unroll
        for (int i = 0; i < S_STAT; ++i) o8 += st[i] * wms[i * OUT_DIM + s];
        out[(size_t)traj * OUT_DIM + s] = o8 + b_mlp[s];
    }
}

extern "C" void kernel_launch(void* const* d_in, const int* in_sizes, int n_in,
                              void* d_out, int out_size, void* d_ws, size_t ws_size,
                              hipStream_t stream) {
    const float* data        = (const float*)d_in[0];
    const float* time_steps  = (const float*)d_in[1];
    const float* static_data = (const float*)d_in[2];
    const float* W_update    = (const float*)d_in[3];
    const float* b_update    = (const float*)d_in[4];
    const float* W_reset     = (const float*)d_in[5];
    const float* b_reset     = (const float*)d_in[6];
    const float* W_new       = (const float*)d_in[7];
    const float* b_new       = (const float*)d_in[8];
    const float* W_emit      = (const float*)d_in[9];
    const float* b_emit      = (const float*)d_in[10];
    const float* W_ode       = (const float*)d_in[11];
    const float* b_ode       = (const float*)d_in[12];
    const float* W_mlp       = (const float*)d_in[13];
    const float* b_mlp       = (const float*)d_in[14];
    float* out = (float*)d_out;

    // 8 trajectories per 256-thread block -> 2048 blocks, 8192 waves
    dim3 grid(B_TRAJ / 8), block(256);
    hipLaunchKernelGGL(dgm2_32lane, grid, block, 0, stream,
                       data, time_steps, static_data,
                       W_update, b_update, W_reset, b_reset, W_new, b_new,
                       W_emit, b_emit, W_ode, b_ode, W_mlp, b_mlp, out);
}

// Round 4
// 415.217 us; speedup vs baseline: 2.8694x; 1.1327x over previous
//
#include <hip/hip_runtime.h>
#include <math.h>

// Problem constants (from reference)
#define B_TRAJ 16384
#define T_STEPS 60
#define D_IN 36
#define L_DIM 10
#define C_NUM 20
#define S_STAT 9
#define OUT_DIM 8
#define TT 5
#define NTILE (T_STEPS / TT)   // 12

__device__ __forceinline__ float rcp_fast(float x) { return __builtin_amdgcn_rcpf(x); }
__device__ __forceinline__ float sigm_fast(float x) { return rcp_fast(1.0f + __expf(-x)); }
__device__ __forceinline__ float tanh_fast(float x) {
    x = fminf(fmaxf(x, -10.0f), 10.0f);
    float e = __expf(2.0f * x);
    return (e - 1.0f) * rcp_fast(e + 1.0f);
}
#define WFENCE() __builtin_amdgcn_wave_barrier()

// Phase 1: per-wave precompute of the gate x-projections (no seq dependency):
//   xproj[ltraj][t][c] = x_t . Wx[:,c]   (c<10: W_update, <20: W_reset, <30: W_new)
// Phase 2: sequential 60-step scan; per-lane x-part is ONE LDS read.
// Lane roles (s = lane & 31): s<10 u-col (+ODE col, +head col for s<8),
// 10..19 r-col (+emit col s-10), 20..29 n-col (+emit col s-10), 30/31 inert.
// Softmax is carried UNNORMALIZED (z); normalization folds into next step's
// dot via zdot * rcp(zsum) — no cross-lane reduction at all.
__global__ __launch_bounds__(256) __attribute__((amdgpu_waves_per_eu(2, 2)))
void dgm2_xsplit(
    const float* __restrict__ data,        // [B, T, D]
    const float* __restrict__ time_steps,  // [T]
    const float* __restrict__ static_data, // [B, S]
    const float* __restrict__ W_update,    // [46, 10]
    const float* __restrict__ b_update,
    const float* __restrict__ W_reset,     // [46, 10]
    const float* __restrict__ b_reset,
    const float* __restrict__ W_new,       // [46, 10]
    const float* __restrict__ b_new,
    const float* __restrict__ W_emit,      // [30, 20]
    const float* __restrict__ b_emit,
    const float* __restrict__ W_ode,       // [10, 10]
    const float* __restrict__ b_ode,
    const float* __restrict__ W_mlp,       // [609, 8]
    const float* __restrict__ b_mlp,
    float* __restrict__ out)               // [B, 8]
{
    __shared__ __align__(16) float xproj[8][T_STEPS][30];      // 57600 B
    __shared__ __align__(16) float xstage[2][4][2][TT][36];    // 11520 B (dbuf)
    __shared__ __align__(16) float WGX[D_IN][32];              // 4608 B
    __shared__ __align__(16) float bcYI[4][2][12];
    __shared__ __align__(16) float bcR [4][2][12];
    __shared__ __align__(16) float bcN [4][2][12];
    __shared__ __align__(16) float bcY [4][2][12];
    __shared__ __align__(16) float bcP [4][2][20];
    __shared__ float dts[T_STEPS];

    const int tid  = threadIdx.x;
    const int w    = tid >> 6;
    const int lane = tid & 63;
    const int half = lane >> 5;
    const int s    = lane & 31;
    const int ltraj = w * 2 + half;
    const int traj  = blockIdx.x * 8 + ltraj;

    // ---- block-wide one-time staging: WGX (x-part weights, col-per-lane) + dts ----
    for (int i = tid; i < D_IN * 30; i += 256) {
        const int k = i / 30, c = i % 30;
        float v;
        if (c < 10)      v = W_update[(L_DIM + k) * L_DIM + c];
        else if (c < 20) v = W_reset [(L_DIM + k) * L_DIM + (c - 10)];
        else             v = W_new   [(L_DIM + k) * L_DIM + (c - 20)];
        WGX[k][c] = v;
    }
    for (int i = tid; i < D_IN * 2; i += 256) WGX[i >> 1][30 + (i & 1)] = 0.0f;
    if (tid < T_STEPS) dts[tid] = (tid == 0) ? 0.01f : time_steps[tid] - time_steps[tid - 1];
    __syncthreads();

    // ================= Phase 1: xproj precompute (wave-local) =================
    {
        float wxp[D_IN];            // own column's x-part weights (phase-1-only live range)
#pragma unroll
        for (int k = 0; k < D_IN; ++k) wxp[k] = WGX[k][s];

        // stage tile 0
        {
            const float* src = data + (size_t)(blockIdx.x * 8 + w * 2) * (T_STEPS * D_IN);
            for (int i = lane; i < 2 * TT * 9; i += 64) {
                const int h = i / (TT * 9), j = i % (TT * 9);
                const float4 v = *reinterpret_cast<const float4*>(
                    src + (size_t)h * (T_STEPS * D_IN) + j * 4);
                *reinterpret_cast<float4*>(&xstage[0][w][h][0][0] + j * 4) = v;
            }
        }
        WFENCE();

        for (int tile = 0; tile < NTILE; ++tile) {
            const int cb = tile & 1, nb = cb ^ 1;
            // prefetch next tile into regs
            float4 pfa = make_float4(0.f, 0.f, 0.f, 0.f);
            float4 pfb = make_float4(0.f, 0.f, 0.f, 0.f);
            if (tile + 1 < NTILE) {
                const float* src = data +
                    ((size_t)(blockIdx.x * 8 + w * 2) * T_STEPS + (tile + 1) * TT) * D_IN;
                { const int h = lane / 45, j = lane % 45;
                  pfa = *reinterpret_cast<const float4*>(src + (size_t)h * (T_STEPS * D_IN) + j * 4); }
                if (lane < 26) {
                  const int i = lane + 64; const int h = i / 45, j = i % 45;
                  pfb = *reinterpret_cast<const float4*>(src + (size_t)h * (T_STEPS * D_IN) + j * 4); }
            }
            // compute current tile
            const int t0 = tile * TT;
#pragma unroll
            for (int tt = 0; tt < TT; ++tt) {
                float acc = 0.0f;
#pragma unroll
                for (int c = 0; c < 9; ++c) {
                    const float4 x4 = *reinterpret_cast<const float4*>(&xstage[cb][w][half][tt][c * 4]);
                    acc += x4.x * wxp[c * 4]     + x4.y * wxp[c * 4 + 1]
                         + x4.z * wxp[c * 4 + 2] + x4.w * wxp[c * 4 + 3];
                }
                if (s < 30) xproj[ltraj][t0 + tt][s] = acc;
            }
            // commit prefetched tile
            if (tile + 1 < NTILE) {
                { const int h = lane / 45, j = lane % 45;
                  *reinterpret_cast<float4*>(&xstage[nb][w][h][0][0] + j * 4) = pfa; }
                if (lane < 26) {
                  const int i = lane + 64; const int h = i / 45, j = i % 45;
                  *reinterpret_cast<float4*>(&xstage[nb][w][h][0][0] + j * 4) = pfb; }
            }
            WFENCE();
        }
    }

    // ================= Phase 2: sequential scan =================
    const bool uo = (s < 10);
    const bool ro = (s >= 10 && s < 20);
    const bool no = (s >= 20 && s < 30);
    const bool eo = (s >= 10 && s < 30);
    const bool oo = (s < OUT_DIM);
    const int  gcol = uo ? s : (ro ? (s - 10) : (no ? (s - 20) : 0));

    const float* Wg = uo ? W_update : (ro ? W_reset : W_new);
    float wgy[L_DIM];                       // y-part of own gate column
#pragma unroll
    for (int k = 0; k < L_DIM; ++k) wgy[k] = (s < 30) ? Wg[k * L_DIM + gcol] : 0.0f;

    float waux[30];                          // eo: emit col; uo: [0..9]=ODE col, [10..19]=W_mlp stream
#pragma unroll
    for (int k = 0; k < 30; ++k) {
        float v = 0.0f;
        if (eo) v = W_emit[k * C_NUM + (s - 10)];
        else if (uo && k < L_DIM) v = W_ode[k * L_DIM + s];
        waux[k] = v;
    }
    if (oo) {
#pragma unroll
        for (int l = 0; l < L_DIM; ++l) waux[10 + l] = W_mlp[l * OUT_DIM + s];
    }
    const float bg    = uo ? b_update[s] : (ro ? b_reset[gcol] : (no ? b_new[gcol] : 0.0f));
    const float bode  = uo ? b_ode[s] : 0.0f;
    const float bemit = eo ? b_emit[s - 10] : 0.0f;

    float y[L_DIM];
#pragma unroll
    for (int k = 0; k < L_DIM; ++k) y[k] = 0.0f;
    float yown = 0.0f, o8 = 0.0f;
    if (eo) bcP[w][half][s - 10] = 0.0f;     // carried z (unnormalized); 0 => p=0 at t=0
    WFENCE();

    for (int t = 0; t < T_STEPS; ++t) {
        const float dt = dts[t];

        // ---- ODE: yi_s = y_s + tanh(b + y.Wode_col_s)*dt (uo lanes) ----
        float g = bode;
#pragma unroll
        for (int k = 0; k < L_DIM; ++k) g += y[k] * waux[k];
        const float yis = yown + tanh_fast(g) * dt;
        if (uo) bcYI[w][half][s] = yis;
        WFENCE();
        {
            const float4 a = *reinterpret_cast<const float4*>(&bcYI[w][half][0]);
            const float4 b = *reinterpret_cast<const float4*>(&bcYI[w][half][4]);
            const float2 c = *reinterpret_cast<const float2*>(&bcYI[w][half][8]);
            y[0] = a.x; y[1] = a.y; y[2] = a.z; y[3] = a.w;
            y[4] = b.x; y[5] = b.y; y[6] = b.z; y[7] = b.w;
            y[8] = c.x; y[9] = c.y;
        }

        // ---- gates: pre-activation = bg + xproj + y-part ----
        const float xa = xproj[ltraj][t][(s < 30) ? s : 0];
        const float accB = bg + xa;
        float accY = 0.0f;
#pragma unroll
        for (int k = 0; k < L_DIM; ++k) accY += y[k] * wgy[k];
        const float uval = sigm_fast(accB + accY);   // u on uo lanes, r on ro lanes
        if (ro) bcR[w][half][s - 10] = uval;
        WFENCE();

        // ---- candidate on n lanes: accB + sum (yi_k r_k) wn_k ----
        float accN = accB;
        {
            const float4 a = *reinterpret_cast<const float4*>(&bcR[w][half][0]);
            const float4 b = *reinterpret_cast<const float4*>(&bcR[w][half][4]);
            const float2 c = *reinterpret_cast<const float2*>(&bcR[w][half][8]);
            const float rv[L_DIM] = {a.x, a.y, a.z, a.w, b.x, b.y, b.z, b.w, c.x, c.y};
#pragma unroll
            for (int k = 0; k < L_DIM; ++k) accN += (y[k] * rv[k]) * wgy[k];
        }
        if (no) bcN[w][half][s - 20] = accN;
        WFENCE();

        // ---- blend on u lanes: yn = n + u*(yi - n) ----
        if (uo) {
            const float nv = bcN[w][half][s];
            const float yn = nv + uval * (yis - nv);
            yown = yn;
            bcY[w][half][s] = yn;
        }
        WFENCE();
        {
            const float4 a = *reinterpret_cast<const float4*>(&bcY[w][half][0]);
            const float4 b = *reinterpret_cast<const float4*>(&bcY[w][half][4]);
            const float2 c = *reinterpret_cast<const float2*>(&bcY[w][half][8]);
            y[0] = a.x; y[1] = a.y; y[2] = a.z; y[3] = a.w;
            y[4] = b.x; y[5] = b.y; y[6] = b.z; y[7] = b.w;
            y[8] = c.x; y[9] = c.y;
        }

        // ---- emitter: logit = b + (z_prev . We_p) / sum(z_prev) + y . We_y ----
        float zdot = 0.0f, zsum = 0.0f;
#pragma unroll
        for (int q = 0; q < 5; ++q) {
            const float4 z4 = *reinterpret_cast<const float4*>(&bcP[w][half][q * 4]);
            zdot += z4.x * waux[q * 4]     + z4.y * waux[q * 4 + 1]
                  + z4.z * waux[q * 4 + 2] + z4.w * waux[q * 4 + 3];
            zsum += (z4.x + z4.y) + (z4.z + z4.w);
        }
        const float pinv = (t == 0) ? 0.0f : rcp_fast(zsum);
        float ev = bemit + zdot * pinv;
#pragma unroll
        for (int k = 0; k < L_DIM; ++k) ev += y[k] * waux[20 + k];
        const float zv = __expf(fminf(ev, 60.0f));

        // ---- fused head on oo lanes; stream next W_mlp column ----
        if (oo) {
#pragma unroll
            for (int l = 0; l < L_DIM; ++l) o8 += y[l] * waux[10 + l];
        }
        if (eo) bcP[w][half][s - 10] = zv;
        if (oo && t + 1 < T_STEPS) {
#pragma unroll
            for (int l = 0; l < L_DIM; ++l)
                waux[10 + l] = W_mlp[((size_t)(t + 1) * L_DIM + l) * OUT_DIM + s];
        }
        WFENCE();
    }

    // ---- static tail + bias + store ----
    if (oo) {
        const float* stp = static_data + (size_t)traj * S_STAT;
        const float* wms = W_mlp + (size_t)(T_STEPS * L_DIM) * OUT_DIM;
#pragma unroll
        for (int i = 0; i < S_STAT; ++i) o8 += stp[i] * wms[i * OUT_DIM + s];
        out[(size_t)traj * OUT_DIM + s] = o8 + b_mlp[s];
    }
}

extern "C" void kernel_launch(void* const* d_in, const int* in_sizes, int n_in,
                              void* d_out, int out_size, void* d_ws, size_t ws_size,
                              hipStream_t stream) {
    const float* data        = (const float*)d_in[0];
    const float* time_steps  = (const float*)d_in[1];
    const float* static_data = (const float*)d_in[2];
    const float* W_update    = (const float*)d_in[3];
    const float* b_update    = (const float*)d_in[4];
    const float* W_reset     = (const float*)d_in[5];
    const float* b_reset     = (const float*)d_in[6];
    const float* W_new       = (const float*)d_in[7];
    const float* b_new       = (const float*)d_in[8];
    const float* W_emit      = (const float*)d_in[9];
    const float* b_emit      = (const float*)d_in[10];
    const float* W_ode       = (const float*)d_in[11];
    const float* b_ode       = (const float*)d_in[12];
    const float* W_mlp       = (const float*)d_in[13];
    const float* b_mlp       = (const float*)d_in[14];
    float* out = (float*)d_out;

    // 8 trajectories per 256-thread block -> 2048 blocks, 8192 waves
    dim3 grid(B_TRAJ / 8), block(256);
    hipLaunchKernelGGL(dgm2_xsplit, grid, block, 0, stream,
                       data, time_steps, static_data,
                       W_update, b_update, W_reset, b_reset, W_new, b_new,
                       W_emit, b_emit, W_ode, b_ode, W_mlp, b_mlp, out);
}

// Round 5
// 343.485 us; speedup vs baseline: 3.4687x; 1.2088x over previous
//
#include <hip/hip_runtime.h>
#include <hip/hip_fp16.h>
#include <math.h>

// Problem constants (from reference)
#define B_TRAJ 16384
#define T_STEPS 60
#define D_IN 36
#define L_DIM 10
#define C_NUM 20
#define S_STAT 9
#define OUT_DIM 8
#define TT 2
#define NTILE (T_STEPS / TT)   // 30

__device__ __forceinline__ float rcp_fast(float x) { return __builtin_amdgcn_rcpf(x); }
__device__ __forceinline__ float sigm_fast(float x) { return rcp_fast(1.0f + __expf(-x)); }
__device__ __forceinline__ float tanh_fast(float x) {
    x = fminf(fmaxf(x, -10.0f), 10.0f);
    float e = __expf(2.0f * x);
    return (e - 1.0f) * rcp_fast(e + 1.0f);
}
#define WFENCE() __builtin_amdgcn_wave_barrier()

// Phase 1: per-wave precompute xproj[traj][t][c] = x_t . Wx[:,c] (f16 in LDS).
// Phase 2: sequential scan; per-lane x-part is ONE f16 LDS read; y_t written
//          back (f16) into the consumed xproj[t] slot for phase 3.
// Phase 3: deferred MLP head — 4 t-groups x 8 cols across 32 lanes, 2-shuffle reduce.
// Lane roles (s = lane & 31): s<10 u-col (+ODE col), 10..19 r-col (+emit col),
// 20..29 n-col (+emit col), 30/31 inert. Softmax carried UNNORMALIZED.
// All phase-2/3 sync is intra-wave (in-order LDS + wave_barrier).
__global__ __launch_bounds__(256) __attribute__((amdgpu_waves_per_eu(4, 8)))
void dgm2_v5(
    const float* __restrict__ data,        // [B, T, D]
    const float* __restrict__ time_steps,  // [T]
    const float* __restrict__ static_data, // [B, S]
    const float* __restrict__ W_update,    // [46, 10]
    const float* __restrict__ b_update,
    const float* __restrict__ W_reset,     // [46, 10]
    const float* __restrict__ b_reset,
    const float* __restrict__ W_new,       // [46, 10]
    const float* __restrict__ b_new,
    const float* __restrict__ W_emit,      // [30, 20]
    const float* __restrict__ b_emit,
    const float* __restrict__ W_ode,       // [10, 10]
    const float* __restrict__ b_ode,
    const float* __restrict__ W_mlp,       // [609, 8]
    const float* __restrict__ b_mlp,
    float* __restrict__ out)               // [B, 8]
{
    __shared__ __align__(16) __half xprojH[8][61][32];   // 31232 B (t-dim padded: halves 16 banks apart)
    __shared__ __align__(16) float WGX[D_IN][32];        // 4608 B (phase-1 x-weights, col per lane)
    __shared__ __align__(16) float wbuf[4][292];         // 4672 B per-wave scratch:
                                                          //  phase1: xstage [buf][half][tt][36] (288 f)
                                                          //  phase2: bc @ 0/24/48/72 (+half*12), bcP @ 96 (+half*20)
    __shared__ float dts[T_STEPS];

    const int tid  = threadIdx.x;
    const int w    = tid >> 6;
    const int lane = tid & 63;
    const int half = lane >> 5;
    const int s    = lane & 31;
    const int ltraj = w * 2 + half;
    const int traj  = blockIdx.x * 8 + ltraj;

    // ---- block-wide one-time: WGX + dts ----
    for (int i = tid; i < D_IN * 30; i += 256) {
        const int k = i / 30, c = i % 30;
        float v;
        if (c < 10)      v = W_update[(L_DIM + k) * L_DIM + c];
        else if (c < 20) v = W_reset [(L_DIM + k) * L_DIM + (c - 10)];
        else             v = W_new   [(L_DIM + k) * L_DIM + (c - 20)];
        WGX[k][c] = v;
    }
    for (int i = tid; i < D_IN * 2; i += 256) WGX[i >> 1][30 + (i & 1)] = 0.0f;
    if (tid < T_STEPS) dts[tid] = (tid == 0) ? 0.01f : time_steps[tid] - time_steps[tid - 1];
    __syncthreads();

    // ================= Phase 1: xproj precompute (wave-local) =================
    {
        float wxp[D_IN];
#pragma unroll
        for (int k = 0; k < D_IN; ++k) wxp[k] = WGX[k][s];

        float* xst = &wbuf[w][0];   // [buf][half][tt][36]
        const float* tbase = data + (size_t)(blockIdx.x * 8 + w * 2) * (T_STEPS * D_IN);
        const int sh  = lane / 18;      // staging half
        const int sr  = lane % 18;
        const int stt = sr / 9;         // timestep within tile
        const int sc  = sr % 9;         // float4 chunk
        const bool stg = (lane < 36);

        if (stg) {
            const float4 v = *reinterpret_cast<const float4*>(
                tbase + (size_t)sh * (T_STEPS * D_IN) + stt * D_IN + sc * 4);
            *reinterpret_cast<float4*>(xst + ((0 * 2 + sh) * TT + stt) * 36 + sc * 4) = v;
        }
        WFENCE();

        for (int tile = 0; tile < NTILE; ++tile) {
            const int cb = tile & 1, nb = cb ^ 1;
            float4 pf = make_float4(0.f, 0.f, 0.f, 0.f);
            if (stg && (tile + 1 < NTILE)) {
                pf = *reinterpret_cast<const float4*>(
                    tbase + (size_t)sh * (T_STEPS * D_IN) + ((tile + 1) * TT + stt) * D_IN + sc * 4);
            }
#pragma unroll
            for (int tt = 0; tt < TT; ++tt) {
                const float* xrow = xst + ((cb * 2 + half) * TT + tt) * 36;
                float acc = 0.0f;
#pragma unroll
                for (int c = 0; c < 9; ++c) {
                    const float4 x4 = *reinterpret_cast<const float4*>(xrow + c * 4);
                    acc += x4.x * wxp[c * 4]     + x4.y * wxp[c * 4 + 1]
                         + x4.z * wxp[c * 4 + 2] + x4.w * wxp[c * 4 + 3];
                }
                if (s < 30) xprojH[ltraj][tile * TT + tt][s] = __float2half(acc);
            }
            if (stg && (tile + 1 < NTILE)) {
                *reinterpret_cast<float4*>(xst + ((nb * 2 + sh) * TT + stt) * 36 + sc * 4) = pf;
            }
            WFENCE();
        }
    }

    // ================= Phase 2: sequential scan =================
    const bool uo = (s < 10);
    const bool ro = (s >= 10 && s < 20);
    const bool no = (s >= 20 && s < 30);
    const bool eo = (s >= 10 && s < 30);
    const int  gcol = uo ? s : (ro ? (s - 10) : (no ? (s - 20) : 0));

    const float* Wg = uo ? W_update : (ro ? W_reset : W_new);
    float wgy[L_DIM];
#pragma unroll
    for (int k = 0; k < L_DIM; ++k) wgy[k] = (s < 30) ? Wg[k * L_DIM + gcol] : 0.0f;

    float waux[30];     // eo: emit col; uo: [0..9] = ODE col
#pragma unroll
    for (int k = 0; k < 30; ++k) {
        float v = 0.0f;
        if (eo) v = W_emit[k * C_NUM + (s - 10)];
        else if (uo && k < L_DIM) v = W_ode[k * L_DIM + s];
        waux[k] = v;
    }
    const float bg    = uo ? b_update[s] : (ro ? b_reset[gcol] : (no ? b_new[gcol] : 0.0f));
    const float bode  = uo ? b_ode[s] : 0.0f;
    const float bemit = eo ? b_emit[s - 10] : 0.0f;

    // per-wave bc views inside wbuf
    float* bcYI = &wbuf[w][0]  + half * 12;
    float* bcR  = &wbuf[w][24] + half * 12;
    float* bcN  = &wbuf[w][48] + half * 12;
    float* bcY  = &wbuf[w][72] + half * 12;
    float* bcP  = &wbuf[w][96] + half * 20;

    float y[L_DIM];
#pragma unroll
    for (int k = 0; k < L_DIM; ++k) y[k] = 0.0f;
    float yown = 0.0f;
    if (eo) bcP[s - 10] = 0.0f;     // carried unnormalized z; 0 => p=0 at t=0
    WFENCE();

    for (int t = 0; t < T_STEPS; ++t) {
        const float dt = dts[t];

        // ---- ODE: yi_s = y_s + tanh(b + y.Wode_col_s)*dt (uo lanes) ----
        float g = bode;
#pragma unroll
        for (int k = 0; k < L_DIM; ++k) g += y[k] * waux[k];
        const float yis = fmaf(tanh_fast(g), dt, yown);
        if (uo) bcYI[s] = yis;
        WFENCE();
        {
            const float4 a = *reinterpret_cast<const float4*>(bcYI);
            const float4 b = *reinterpret_cast<const float4*>(bcYI + 4);
            const float2 c = *reinterpret_cast<const float2*>(bcYI + 8);
            y[0] = a.x; y[1] = a.y; y[2] = a.z; y[3] = a.w;
            y[4] = b.x; y[5] = b.y; y[6] = b.z; y[7] = b.w;
            y[8] = c.x; y[9] = c.y;
        }

        // ---- gates: pre-activation = bg + xproj(f16) + y-part ----
        const float xa = __half2float(xprojH[ltraj][t][s]);
        const float accB = bg + xa;
        float accY = 0.0f;
#pragma unroll
        for (int k = 0; k < L_DIM; ++k) accY += y[k] * wgy[k];
        const float uval = sigm_fast(accB + accY);   // u on uo, r on ro
        if (ro) bcR[s - 10] = uval;
        WFENCE();

        // ---- candidate: accB + sum (yi_k r_k) wn_k ----
        float accN = accB;
        {
            const float4 a = *reinterpret_cast<const float4*>(bcR);
            const float4 b = *reinterpret_cast<const float4*>(bcR + 4);
            const float2 c = *reinterpret_cast<const float2*>(bcR + 8);
            const float rv[L_DIM] = {a.x, a.y, a.z, a.w, b.x, b.y, b.z, b.w, c.x, c.y};
#pragma unroll
            for (int k = 0; k < L_DIM; ++k) accN += (y[k] * rv[k]) * wgy[k];
        }
        if (no) bcN[s - 20] = accN;
        WFENCE();

        // ---- blend on u lanes: yn = n + u*(yi - n); stash y_t (f16) for head ----
        if (uo) {
            const float nv = bcN[s];
            const float yn = fmaf(uval, yis - nv, nv);
            yown = yn;
            bcY[s] = yn;
            xprojH[ltraj][t][s] = __float2half(yn);   // xproj[t] consumed above
        }
        WFENCE();
        {
            const float4 a = *reinterpret_cast<const float4*>(bcY);
            const float4 b = *reinterpret_cast<const float4*>(bcY + 4);
            const float2 c = *reinterpret_cast<const float2*>(bcY + 8);
            y[0] = a.x; y[1] = a.y; y[2] = a.z; y[3] = a.w;
            y[4] = b.x; y[5] = b.y; y[6] = b.z; y[7] = b.w;
            y[8] = c.x; y[9] = c.y;
        }

        // ---- emitter: logit = b + (z_prev . We_p)/sum(z_prev) + y . We_y ----
        float zdot = 0.0f, zsum = 0.0f;
#pragma unroll
        for (int q = 0; q < 5; ++q) {
            const float4 z4 = *reinterpret_cast<const float4*>(bcP + q * 4);
            zdot += z4.x * waux[q * 4]     + z4.y * waux[q * 4 + 1]
                  + z4.z * waux[q * 4 + 2] + z4.w * waux[q * 4 + 3];
            zsum += (z4.x + z4.y) + (z4.z + z4.w);
        }
        const float pinv = (t == 0) ? 0.0f : rcp_fast(zsum);
        float ev = fmaf(zdot, pinv, bemit);
#pragma unroll
        for (int k = 0; k < L_DIM; ++k) ev += y[k] * waux[20 + k];
        const float zv = __expf(fminf(ev, 60.0f));
        if (eo) bcP[s - 10] = zv;
        WFENCE();
    }

    // ================= Phase 3: deferred MLP head =================
    // 32 lanes per traj: group g = s>>3 handles t = g, g+4, ...; col = s&7.
    WFENCE();
    {
        const int g = s >> 3, col = s & 7;
        float o8 = 0.0f;
        for (int tb = 0; tb < 15; ++tb) {
            const int t = g + tb * 4;
            const __half2* yh = reinterpret_cast<const __half2*>(&xprojH[ltraj][t][0]);
            const float* wrow = W_mlp + (size_t)t * L_DIM * OUT_DIM + col;
#pragma unroll
            for (int q = 0; q < 5; ++q) {
                const float2 yv = __half22float2(yh[q]);
                o8 += yv.x * wrow[(2 * q) * OUT_DIM] + yv.y * wrow[(2 * q + 1) * OUT_DIM];
            }
        }
        o8 += __shfl_xor(o8, 8, 32);
        o8 += __shfl_xor(o8, 16, 32);
        if (s < OUT_DIM) {
            const float* stp = static_data + (size_t)traj * S_STAT;
            const float* wms = W_mlp + (size_t)(T_STEPS * L_DIM) * OUT_DIM;
#pragma unroll
            for (int i = 0; i < S_STAT; ++i) o8 += stp[i] * wms[i * OUT_DIM + s];
            out[(size_t)traj * OUT_DIM + s] = o8 + b_mlp[s];
        }
    }
}

extern "C" void kernel_launch(void* const* d_in, const int* in_sizes, int n_in,
                              void* d_out, int out_size, void* d_ws, size_t ws_size,
                              hipStream_t stream) {
    const float* data        = (const float*)d_in[0];
    const float* time_steps  = (const float*)d_in[1];
    const float* static_data = (const float*)d_in[2];
    const float* W_update    = (const float*)d_in[3];
    const float* b_update    = (const float*)d_in[4];
    const float* W_reset     = (const float*)d_in[5];
    const float* b_reset     = (const float*)d_in[6];
    const float* W_new       = (const float*)d_in[7];
    const float* b_new       = (const float*)d_in[8];
    const float* W_emit      = (const float*)d_in[9];
    const float* b_emit      = (const float*)d_in[10];
    const float* W_ode       = (const float*)d_in[11];
    const float* b_ode       = (const float*)d_in[12];
    const float* W_mlp       = (const float*)d_in[13];
    const float* b_mlp       = (const float*)d_in[14];
    float* out = (float*)d_out;

    // 8 trajectories per 256-thread block -> 2048 blocks, 8192 waves
    dim3 grid(B_TRAJ / 8), block(256);
    hipLaunchKernelGGL(dgm2_v5, grid, block, 0, stream,
                       data, time_steps, static_data,
                       W_update, b_update, W_reset, b_reset, W_new, b_new,
                       W_emit, b_emit, W_ode, b_ode, W_mlp, b_mlp, out);
}